// Round 8
// baseline (56.102 us; speedup 1.0000x reference)
//
#include <hip/hip_runtime.h>
#include <math.h>

#define BB 2
#define LL 5
#define NN 10
#define CC 64
#define HH 128
#define WW 256
#define PP (HH*WW)          // 32768
#define NP (NN*PP)          // 327680

// ---------------- ws float layout ----------------
// [0..127]      gate (B*C)
// [128..1151]   cntp (1024 per-block mask-count partials)
// [2048..67583]       partS [1024][64]
// [67584..133119]     partM [1024][64]

// stencil + scores + softmax + fuse + stat partials; x read exactly once.
// Core x/softmax/f loop is EXACT R3 structure: plain __launch_bounds__(256),
// no min-waves (R6 regression), no global atomics (R5 regression).
__global__ __launch_bounds__(256) void k_attnfuse(const float* __restrict__ x,
                                                  const float* __restrict__ psm,
                                                  const float* __restrict__ inv_delay,
                                                  const float* __restrict__ ew_w,
                                                  const float* __restrict__ ew_b,
                                                  const float* __restrict__ ewc_w,
                                                  const float* __restrict__ ewc_b,
                                                  float* __restrict__ out,
                                                  float* __restrict__ partS,
                                                  float* __restrict__ partM,
                                                  float* __restrict__ cntp) {
    const float g0 = 0.15915494309189535f;
    const float g1 = 0.09653235263005391f;
    const float g2 = 0.05854983152431917f;
    const float g4 = 0.02153927930184936f;
    const float g5 = 0.01306423328468446f;
    const float g8 = 0.00291502449738744f;
    const float G[25] = { g8,g5,g4,g5,g8,
                          g5,g2,g1,g2,g5,
                          g4,g1,g0,g1,g4,
                          g5,g2,g1,g2,g5,
                          g8,g5,g4,g5,g8 };

    int blk = blockIdx.x;
    int b   = blk >> 9;                 // 512 blocks per batch
    int tid  = threadIdx.x;
    int lane = tid & 63;
    int wv   = tid >> 6;
    int pblock = blk & 511;
    int p = (pblock << 6) + lane;
    int h  = pblock >> 2;               // pixel row (64 | 256)
    int c0 = (pblock & 3) << 6;         // first col of this block

    __shared__ float cs[5 * 5 * 68];    // [agent][row r][col c0-2+cc]
    __shared__ float encs[5], enws[5];
    if (tid < 5)
        encs[tid] = tanhf(inv_delay[b * LL + tid] * ewc_w[0] + ewc_b[0]) + 1.0f;
    else if (tid < 10)
        enws[tid - 5] = tanhf(inv_delay[b * LL + tid - 5] * ew_w[0] + ew_b[0]) + 1.0f;
    __syncthreads();

    // conf halo: 5 agents x 5 rows x 68 cols, recomputed from psm (L2/L3-hot)
    for (int idx = tid; idx < 1700; idx += 256) {
        int l   = idx / 340;
        int rem = idx - l * 340;
        int r   = rem / 68;
        int cc2 = rem - r * 68;
        int row = h - 2 + r;
        int col = c0 - 2 + cc2;
        float v = 0.0f;
        if ((unsigned)row < (unsigned)HH && (unsigned)col < (unsigned)WW) {
            int n = b * LL + l;
            float a0 = psm[(n * 2 + 0) * PP + row * WW + col];
            float a1 = psm[(n * 2 + 1) * PP + row * WW + col];
            v = fmaxf(1.0f / (1.0f + expf(-a0)), 1.0f / (1.0f + expf(-a1))) * encs[l];
        }
        cs[idx] = v;
    }
    __syncthreads();

    // per-lane gaussian + threshold for all 5 agents (each wave redundant)
    float mv[5];
#pragma unroll
    for (int l = 0; l < LL; ++l) {
        float acc = 0.0f;
#pragma unroll
        for (int r = 0; r < 5; ++r)
#pragma unroll
            for (int dx = 0; dx < 5; ++dx)
                acc += cs[l * 340 + r * 68 + lane + dx] * G[r * 5 + dx];
        mv[l] = (acc > 0.01f) ? 1.0f : 0.0f;
    }
    mv[0] = 1.0f;                       // ego always communicates

    // mask-count partial (wave 0 only; each (agent,pixel) counted exactly once)
    if (wv == 0) {
        float v = mv[0] + mv[1] + mv[2] + mv[3] + mv[4];
#pragma unroll
        for (int o = 32; o > 0; o >>= 1) v += __shfl_down(v, o, 64);
        if (lane == 0) cntp[blk] = v;
    }

    // ---- R3-exact attention core ----
    const float* xb = x + b * (LL * CC * PP) + p;
    int cbase = wv << 4;

    float xr[16][5];
    float s5[5] = {0.f, 0.f, 0.f, 0.f, 0.f};
#pragma unroll
    for (int cc = 0; cc < 16; ++cc) {
        const float* xc = xb + (cbase + cc) * PP;
#pragma unroll
        for (int l = 0; l < LL; ++l) xr[cc][l] = xc[l * CC * PP];
        float q = xr[cc][0];
#pragma unroll
        for (int l = 0; l < LL; ++l) s5[l] += q * xr[cc][l];
    }

    __shared__ float sred[4][5][64];
#pragma unroll
    for (int l = 0; l < LL; ++l) sred[wv][l][lane] = s5[l];
    __syncthreads();

    float a[5];
    {
        float m[5], t[5], sc[5], e[5];
#pragma unroll
        for (int l = 0; l < LL; ++l) {
            t[l] = sred[0][l][lane] + sred[1][l][lane] + sred[2][l][lane] + sred[3][l][lane];
            m[l] = enws[l] * mv[l];
        }
        const float scale = 0.125f;               // 1/sqrt(64)
#pragma unroll
        for (int l = 0; l < LL; ++l) sc[l] = t[l] * m[0] * m[l] * scale;
        float mxv = fmaxf(fmaxf(fmaxf(sc[0], sc[1]), fmaxf(sc[2], sc[3])), sc[4]);
        float sum = 0.f;
#pragma unroll
        for (int l = 0; l < LL; ++l) { e[l] = expf(sc[l] - mxv); sum += e[l]; }
        float inv = 1.0f / sum;
#pragma unroll
        for (int l = 0; l < LL; ++l) a[l] = e[l] * inv * m[l];
    }

    float* ob = out + b * (CC * PP) + p;
#pragma unroll
    for (int cc = 0; cc < 16; ++cc) {
        float f = 0.f;
#pragma unroll
        for (int l = 0; l < LL; ++l) f += a[l] * xr[cc][l];
        ob[(cbase + cc) * PP] = f;

        // per-block channel stats (no atomics): wave sum/max over 64 pixels
        float sv = f, mm = f;
#pragma unroll
        for (int o = 1; o < 64; o <<= 1) {
            sv += __shfl_xor(sv, o, 64);
            mm = fmaxf(mm, __shfl_xor(mm, o, 64));
        }
        if (lane == 0) {
            partS[blk * CC + cbase + cc] = sv;
            partM[blk * CC + cbase + cc] = mm;
        }
    }
}

// single block: reduce partials -> gate[B*C] and comm_rate
__global__ __launch_bounds__(256) void k_finish(const float* __restrict__ partS,
                                                const float* __restrict__ partM,
                                                const float* __restrict__ cntp,
                                                const float* __restrict__ w1,
                                                const float* __restrict__ w2,
                                                float* __restrict__ gate,
                                                float* __restrict__ comm_out) {
    int t = threadIdx.x;
    int pair = t >> 1;          // (b,c) 0..127
    int sub  = t & 1;
    __shared__ float sS[2][128], sM[2][128];
    {
        int b = pair >> 6, c = pair & 63;
        float s = 0.f, m = -INFINITY;
        int base = b * 512 + sub * 256;
        for (int pb = 0; pb < 256; ++pb) {
            int i = (base + pb) * CC + c;
            s += partS[i];
            m = fmaxf(m, partM[i]);
        }
        sS[sub][pair] = s;
        sM[sub][pair] = m;
    }
    __syncthreads();
    __shared__ float stA[128], stM[128];
    if (t < 128) {
        stA[t] = (sS[0][t] + sS[1][t]) * (1.0f / (float)PP);
        stM[t] = fmaxf(sM[0][t], sM[1][t]);
    }
    __syncthreads();
    __shared__ float hs[BB][4];
    if (t < BB * 4) {
        int b = t >> 2, j = t & 3;
        float ha = 0.f, hm = 0.f;
        for (int c = 0; c < CC; ++c) {
            float wv = w1[j * CC + c];
            ha += stA[b * CC + c] * wv;
            hm += stM[b * CC + c] * wv;
        }
        hs[b][j] = fmaxf(ha, 0.0f) + fmaxf(hm, 0.0f);
    }
    __syncthreads();
    if (t < 128) {
        int b = t >> 6, c = t & 63;
        float g = hs[b][0] * w2[c * 4 + 0] + hs[b][1] * w2[c * 4 + 1]
                + hs[b][2] * w2[c * 4 + 2] + hs[b][3] * w2[c * 4 + 3];
        gate[t] = 1.0f / (1.0f + expf(-g));
    }
    // comm_rate from 1024 block partials
    float s = 0.f;
    for (int j = t; j < 1024; j += 256) s += cntp[j];
#pragma unroll
    for (int o = 32; o > 0; o >>= 1) s += __shfl_down(s, o, 64);
    __shared__ float cred[4];
    if ((t & 63) == 0) cred[t >> 6] = s;
    __syncthreads();
    if (t == 0)
        comm_out[0] = (cred[0] + cred[1] + cred[2] + cred[3]) * (1.0f / (float)NP);
}

// pure scale: out *= gate[b,c]
__global__ __launch_bounds__(256) void k_scale(float* __restrict__ out,
                                               const float* __restrict__ gate) {
    int idx = blockIdx.x * 256 + threadIdx.x;   // < B*C*PP/4
    int bc = idx >> 13;                         // PP/4 = 8192
    float g = gate[bc];
    float4 v = ((float4*)out)[idx];
    v.x *= g; v.y *= g; v.z *= g; v.w *= g;
    ((float4*)out)[idx] = v;
}

extern "C" void kernel_launch(void* const* d_in, const int* in_sizes, int n_in,
                              void* d_out, int out_size, void* d_ws, size_t ws_size,
                              hipStream_t stream) {
    const float* x         = (const float*)d_in[0];
    const float* psm       = (const float*)d_in[1];
    const float* inv_delay = (const float*)d_in[2];
    const float* ew_w      = (const float*)d_in[3];
    const float* ew_b      = (const float*)d_in[4];
    const float* ewc_w     = (const float*)d_in[5];
    const float* ewc_b     = (const float*)d_in[6];
    const float* w1        = (const float*)d_in[7];
    const float* w2        = (const float*)d_in[8];
    float* out = (float*)d_out;
    float* wsf = (float*)d_ws;

    float* gate  = wsf;
    float* cntp  = wsf + 128;
    float* partS = wsf + 2048;
    float* partM = wsf + 2048 + 1024 * CC;

    k_attnfuse<<<1024, 256, 0, stream>>>(x, psm, inv_delay, ew_w, ew_b, ewc_w, ewc_b,
                                         out, partS, partM, cntp);
    k_finish<<<1, 256, 0, stream>>>(partS, partM, cntp, w1, w2, gate, out + BB * CC * PP);
    k_scale<<<BB * CC * PP / 4 / 256, 256, 0, stream>>>(out, gate);
}

// Round 9
// 53.619 us; speedup vs baseline: 1.0463x; 1.0463x over previous
//
#include <hip/hip_runtime.h>
#include <math.h>

#define BB 2
#define LL 5
#define NN 10
#define CC 64
#define HH 128
#define WW 256
#define PP (HH*WW)          // 32768
#define NP (NN*PP)          // 327680

// ---------------- ws float layout ----------------
// [64..319]   avg_part (256)
// [320..575]  mx_part  (256)
// [576..1855] cntp (1280 per-block mask-count partials)
// [4096 .. 4096+NP)  mask

// fused conf+gaussian+threshold stencil: one block per (agent n, row h).
__global__ __launch_bounds__(256) void k_confmask(const float* __restrict__ psm,
                                                  const float* __restrict__ inv_delay,
                                                  const float* __restrict__ ewc_w,
                                                  const float* __restrict__ ewc_b,
                                                  float* __restrict__ mask,
                                                  float* __restrict__ cntp) {
    const float g0 = 0.15915494309189535f;
    const float g1 = 0.09653235263005391f;
    const float g2 = 0.05854983152431917f;
    const float g4 = 0.02153927930184936f;
    const float g5 = 0.01306423328468446f;
    const float g8 = 0.00291502449738744f;
    const float G[25] = { g8,g5,g4,g5,g8,
                          g5,g2,g1,g2,g5,
                          g4,g1,g0,g1,g4,
                          g5,g2,g1,g2,g5,
                          g8,g5,g4,g5,g8 };
    int blk = blockIdx.x;           // 0..1279
    int n   = blk >> 7;             // agent
    int h   = blk & 127;            // row
    int t   = threadIdx.x;          // col
    float enc = tanhf(inv_delay[n] * ewc_w[0] + ewc_b[0]) + 1.0f;
    const float* pn0 = psm + (n * 2 + 0) * PP;
    const float* pn1 = psm + (n * 2 + 1) * PP;

    __shared__ float cs[5][WW];
#pragma unroll
    for (int r = 0; r < 5; ++r) {
        int row = h - 2 + r;
        float v = 0.0f;
        if ((unsigned)row < (unsigned)HH) {
            float a0 = pn0[row * WW + t];
            float a1 = pn1[row * WW + t];
            v = fmaxf(1.0f / (1.0f + expf(-a0)), 1.0f / (1.0f + expf(-a1))) * enc;
        }
        cs[r][t] = v;
    }
    __syncthreads();

    float acc = 0.0f;
#pragma unroll
    for (int r = 0; r < 5; ++r) {
#pragma unroll
        for (int dx = -2; dx <= 2; ++dx) {
            int col = t + dx;
            if ((unsigned)col < (unsigned)WW)
                acc += cs[r][col] * G[r * 5 + (dx + 2)];
        }
    }
    float mv = (acc > 0.01f) ? 1.0f : 0.0f;
    if ((n % LL) == 0) mv = 1.0f;             // ego always communicates
    mask[n * PP + h * WW + t] = mv;

    float v = mv;
#pragma unroll
    for (int o = 32; o > 0; o >>= 1) v += __shfl_down(v, o, 64);
    __shared__ float sred[4];
    int lane = t & 63, wid = t >> 6;
    if (lane == 0) sred[wid] = v;
    __syncthreads();
    if (t == 0) cntp[blk] = sred[0] + sred[1] + sred[2] + sred[3];
}

// scores + softmax + fuse, x read once. 8 waves x 8 channels per 64-pixel
// block: xr is 40 floats/thread (vs 80 at 4x16) -> lower VGPR, double the
// waves issuing loads. Core structure otherwise R3-exact; plain
// __launch_bounds__ (R6: min-waves hurt), no atomics/stat-folds (R5/R8 hurt).
__global__ __launch_bounds__(512) void k_attnfuse(const float* __restrict__ x,
                                                  const float* __restrict__ mask,
                                                  const float* __restrict__ inv_delay,
                                                  const float* __restrict__ ew_w,
                                                  const float* __restrict__ ew_b,
                                                  float* __restrict__ out) {
    int blk = blockIdx.x;
    int b   = blk >> 9;                 // 512 blocks per batch
    int lane = threadIdx.x & 63;
    int wv   = threadIdx.x >> 6;        // 0..7
    int p = ((blk & 511) << 6) + lane;
    const float* xb = x + b * (LL * CC * PP) + p;
    int cbase = wv << 3;                // 8 channels per wave

    float xr[8][5];
    float s5[5] = {0.f, 0.f, 0.f, 0.f, 0.f};
#pragma unroll
    for (int cc = 0; cc < 8; ++cc) {
        const float* xc = xb + (cbase + cc) * PP;
#pragma unroll
        for (int l = 0; l < LL; ++l) xr[cc][l] = xc[l * CC * PP];
        float q = xr[cc][0];
#pragma unroll
        for (int l = 0; l < LL; ++l) s5[l] += q * xr[cc][l];
    }

    __shared__ float sred[8][5][64];
#pragma unroll
    for (int l = 0; l < LL; ++l) sred[wv][l][lane] = s5[l];
    __syncthreads();

    // all waves redundantly finish the softmax (no second sync needed)
    float ew0 = ew_w[0], eb0 = ew_b[0];
    float a[5];
    {
        float m[5], t[5], sc[5], e[5];
#pragma unroll
        for (int l = 0; l < LL; ++l) {
            float tl = 0.f;
#pragma unroll
            for (int w = 0; w < 8; ++w) tl += sred[w][l][lane];
            t[l] = tl;
            float en = tanhf(inv_delay[b * LL + l] * ew0 + eb0) + 1.0f;
            m[l] = en * mask[(b * LL + l) * PP + p];
        }
        const float scale = 0.125f;               // 1/sqrt(64)
#pragma unroll
        for (int l = 0; l < LL; ++l) sc[l] = t[l] * m[0] * m[l] * scale;
        float mxv = fmaxf(fmaxf(fmaxf(sc[0], sc[1]), fmaxf(sc[2], sc[3])), sc[4]);
        float sum = 0.f;
#pragma unroll
        for (int l = 0; l < LL; ++l) { e[l] = expf(sc[l] - mxv); sum += e[l]; }
        float inv = 1.0f / sum;
#pragma unroll
        for (int l = 0; l < LL; ++l) a[l] = e[l] * inv * m[l];
    }

    float* ob = out + b * (CC * PP) + p;
#pragma unroll
    for (int cc = 0; cc < 8; ++cc) {
        float f = 0.f;
#pragma unroll
        for (int l = 0; l < LL; ++l) f += a[l] * xr[cc][l];
        ob[(cbase + cc) * PP] = f;
    }
}

// 256 blocks: block = half of one (b,c) row -> partials (out is L2/L3-warm)
__global__ void k_reduce(const float* __restrict__ xfuse,
                         float* __restrict__ avg_part,
                         float* __restrict__ mx_part) {
    int blk = blockIdx.x;               // 256
    int bc = blk >> 1;
    int half = blk & 1;
    const float4* row = (const float4*)(xfuse + bc * PP) + half * 4096;
    float s = 0.0f, m = -INFINITY;
    for (int i = threadIdx.x; i < 4096; i += 256) {
        float4 v = row[i];
        s += v.x + v.y + v.z + v.w;
        m = fmaxf(m, fmaxf(fmaxf(v.x, v.y), fmaxf(v.z, v.w)));
    }
#pragma unroll
    for (int o = 32; o > 0; o >>= 1) {
        s += __shfl_down(s, o, 64);
        m = fmaxf(m, __shfl_down(m, o, 64));
    }
    __shared__ float ss[4], sm[4];
    int lane = threadIdx.x & 63, wid = threadIdx.x >> 6;
    if (lane == 0) { ss[wid] = s; sm[wid] = m; }
    __syncthreads();
    if (threadIdx.x == 0) {
        avg_part[blk] = ss[0] + ss[1] + ss[2] + ss[3];
        mx_part[blk]  = fmaxf(fmaxf(sm[0], sm[1]), fmaxf(sm[2], sm[3]));
    }
}

// gate (recomputed per block from partials) + scale; block 0 also sums cntp.
__global__ __launch_bounds__(256) void k_scalegate(float* __restrict__ out,
                                                   const float* __restrict__ avg_part,
                                                   const float* __restrict__ mx_part,
                                                   const float* __restrict__ w1,
                                                   const float* __restrict__ w2,
                                                   const float* __restrict__ cntp) {
    int idx = blockIdx.x * 256 + threadIdx.x;   // < B*C*PP/4; block spans ONE (b,c)
    int bc = idx >> 13;                         // PP/4 = 8192
    int b  = bc >> 6;
    int c  = bc & 63;
    __shared__ float hs[4];
    if (threadIdx.x < 4) {
        int j = threadIdx.x;
        float ha = 0.f, hm = 0.f;
        const float invP = 1.0f / (float)PP;
        for (int ch = 0; ch < CC; ++ch) {
            int i = (b * CC + ch) * 2;
            float av = (avg_part[i] + avg_part[i + 1]) * invP;
            float mv = fmaxf(mx_part[i], mx_part[i + 1]);
            float wv = w1[j * CC + ch];
            ha += av * wv;
            hm += mv * wv;
        }
        hs[j] = fmaxf(ha, 0.0f) + fmaxf(hm, 0.0f);
    }
    float4 v = ((float4*)out)[idx];
    __syncthreads();
    float g = hs[0] * w2[c * 4 + 0] + hs[1] * w2[c * 4 + 1]
            + hs[2] * w2[c * 4 + 2] + hs[3] * w2[c * 4 + 3];
    float gate = 1.0f / (1.0f + expf(-g));
    v.x *= gate; v.y *= gate; v.z *= gate; v.w *= gate;
    ((float4*)out)[idx] = v;

    if (blockIdx.x == 0) {
        float s = 0.0f;
        for (int j = threadIdx.x; j < 1280; j += 256) s += cntp[j];
#pragma unroll
        for (int o = 32; o > 0; o >>= 1) s += __shfl_down(s, o, 64);
        __shared__ float cs[4];
        int lane = threadIdx.x & 63, wid = threadIdx.x >> 6;
        if (lane == 0) cs[wid] = s;
        __syncthreads();
        if (threadIdx.x == 0)
            out[BB * CC * PP] = (cs[0] + cs[1] + cs[2] + cs[3]) * (1.0f / (float)NP);
    }
}

extern "C" void kernel_launch(void* const* d_in, const int* in_sizes, int n_in,
                              void* d_out, int out_size, void* d_ws, size_t ws_size,
                              hipStream_t stream) {
    const float* x         = (const float*)d_in[0];
    const float* psm       = (const float*)d_in[1];
    const float* inv_delay = (const float*)d_in[2];
    const float* ew_w      = (const float*)d_in[3];
    const float* ew_b      = (const float*)d_in[4];
    const float* ewc_w     = (const float*)d_in[5];
    const float* ewc_b     = (const float*)d_in[6];
    const float* w1        = (const float*)d_in[7];
    const float* w2        = (const float*)d_in[8];
    float* out = (float*)d_out;
    float* wsf = (float*)d_ws;

    float* avgp = wsf + 64;
    float* mxp  = wsf + 320;
    float* cntp = wsf + 576;
    float* mask = wsf + 4096;

    k_confmask<<<NN * HH, 256, 0, stream>>>(psm, inv_delay, ewc_w, ewc_b, mask, cntp);
    k_attnfuse<<<1024, 512, 0, stream>>>(x, mask, inv_delay, ew_w, ew_b, out);
    k_reduce<<<256, 256, 0, stream>>>(out, avgp, mxp);
    k_scalegate<<<BB * CC * PP / 4 / 256, 256, 0, stream>>>(out, avgp, mxp, w1, w2, cntp);
}